// Round 2
// baseline (16031.029 us; speedup 1.0000x reference)
//
#include <hip/hip_runtime.h>

#define NPOS 65536   // 64 batches * 32 * 32 positions
#define NE   121     // 11*11 tensor entries
#define NP   6       // p-rows per half (P0 = ph*5; row 5 duplicated)

// ------------------------------------------------------------------
// f0: 8-channel 3x3 tensorized conv, 16x16 -> 11x11, writes raw y.
// Grid: 4096 blocks = (b,h) x 2 p-halves, XCD-swizzled so the two
// halves of one (b,h) row land on the same XCD (blockIdx 8 apart).
// Block: 256 thr = (c, w). Each thread: Y[6][11]=66 + A[6][4]=24 regs.
// ------------------------------------------------------------------
__global__ __launch_bounds__(256, 4)
void f0_kernel(const float* __restrict__ x, const float* __restrict__ U,
               const float* __restrict__ V, float* __restrict__ y) {
  __shared__ float smem[2816];                // su(768) + sv(1408); reused for reduce
  int bid = blockIdx.x;
  int wg  = (bid & 7) * 512 + (bid >> 3);     // bijective, 4096 % 8 == 0
  int ph   = wg & 1;                          // p-half; mates are 8 apart in bid
  int row  = wg >> 1;                         // (b,h)
  int b = row >> 5, h = row & 31;
  int P0 = ph * 5;
  int t = threadIdx.x;
  int c = t >> 5, w = t & 31;

  float Y[NP][11];
#pragma unroll
  for (int p = 0; p < NP; ++p)
#pragma unroll
    for (int q = 0; q < 11; ++q) Y[p][q] = 0.f;

  float* su = smem;           // [c][pr][m] : c*96 + pr*16 + m   (768)
  float* sv = smem + 768;     // [c][q][n]  : c*176 + q*16 + n   (1408)

  for (int ij = 0; ij < 9; ++ij) {
    __syncthreads();
    for (int idx = t; idx < 768; idx += 256) {
      int cc = idx / 96, r = idx - cc * 96;
      int pr = r >> 4, m = r & 15;
      su[idx] = U[(cc * 9 + ij) * 176 + (P0 + pr) * 16 + m];
    }
    for (int idx = t; idx < 1408; idx += 256) {
      int cc = idx / 176, qn = idx - cc * 176;
      sv[idx] = V[(cc * 9 + ij) * 176 + qn];
    }
    __syncthreads();
    int i = ij / 3, j = ij - 3 * (ij / 3);
    int hi = h + i - 1, wj = w + j - 1;
    if ((unsigned)hi < 32u && (unsigned)wj < 32u) {
      const float* xb = x + ((size_t)(b * 8 + c) << 18) + (hi << 5) + wj;
      const float* uB = &su[c * 96];
      const float* vB = &sv[c * 176];
      for (int nc = 0; nc < 4; ++nc) {        // n in chunks of 4
        float A[NP][4];
#pragma unroll
        for (int p = 0; p < NP; ++p)
#pragma unroll
          for (int k = 0; k < 4; ++k) A[p][k] = 0.f;
        for (int m = 0; m < 16; ++m) {
          float Xr[4];
#pragma unroll
          for (int k = 0; k < 4; ++k)
            Xr[k] = xb[(m * 16 + nc * 4 + k) << 10];
#pragma unroll
          for (int p = 0; p < NP; ++p) {
            float u = uB[p * 16 + m];
#pragma unroll
            for (int k = 0; k < 4; ++k) A[p][k] += u * Xr[k];
          }
        }
#pragma unroll
        for (int k = 0; k < 4; ++k) {
#pragma unroll
          for (int q = 0; q < 11; ++q) {
            float vv = vB[q * 16 + nc * 4 + k];
#pragma unroll
            for (int p = 0; p < NP; ++p) Y[p][q] += A[p][k] * vv;
          }
        }
      }
    }
  }

  // reduce over c (8 threads per (w,q)) through LDS, one p-row at a time
  int posb = ((b << 5) + h) << 5;
#pragma unroll
  for (int p = 0; p < NP; ++p) {
    __syncthreads();
#pragma unroll
    for (int q = 0; q < 11; ++q) smem[(c * 32 + w) * 11 + q] = Y[p][q];
    __syncthreads();
    for (int idx = t; idx < 352; idx += 256) {
      int qq = idx >> 5, w2 = idx & 31;
      float s = 0.f;
#pragma unroll
      for (int cc = 0; cc < 8; ++cc) s += smem[(cc * 32 + w2) * 11 + qq];
      y[(size_t)((P0 + p) * 11 + qq) * NPOS + posb + w2] = s;
    }
  }
}

// ------------------------------------------------------------------
// TBN stats: partial sums (484 blocks), then finalize scale/shift.
// ------------------------------------------------------------------
__global__ __launch_bounds__(256)
void stats_partial(const float* __restrict__ raw, float* __restrict__ part) {
  int blk = blockIdx.x;
  int e = blk >> 2, qt = blk & 3;
  const float4* p = (const float4*)(raw + (size_t)e * NPOS) + qt * 4096;
  int t = threadIdx.x;
  float s = 0.f, s2 = 0.f;
  for (int i = t; i < 4096; i += 256) {
    float4 v = p[i];
    s  += v.x + v.y + v.z + v.w;
    s2 += v.x * v.x + v.y * v.y + v.z * v.z + v.w * v.w;
  }
#pragma unroll
  for (int o = 32; o > 0; o >>= 1) {
    s  += __shfl_down(s, o);
    s2 += __shfl_down(s2, o);
  }
  __shared__ float ls[8];
  int wid = t >> 6;
  if ((t & 63) == 0) { ls[wid] = s; ls[4 + wid] = s2; }
  __syncthreads();
  if (t == 0) {
    part[blk]       = ls[0] + ls[1] + ls[2] + ls[3];
    part[484 + blk] = ls[4] + ls[5] + ls[6] + ls[7];
  }
}

__global__ void stats_final(const float* __restrict__ part, const float* __restrict__ g,
                            const float* __restrict__ bb, float* __restrict__ sc,
                            float* __restrict__ sh) {
  int e = threadIdx.x;
  if (e < 121) {
    float s  = part[e * 4] + part[e * 4 + 1] + part[e * 4 + 2] + part[e * 4 + 3];
    float s2 = part[484 + e * 4] + part[484 + e * 4 + 1] +
               part[484 + e * 4 + 2] + part[484 + e * 4 + 3];
    float mu  = s  * (1.f / 65536.f);
    float var = s2 * (1.f / 65536.f) - mu * mu;
    float sca = g[e] * rsqrtf(var + 1e-5f);
    sc[e] = sca;
    sh[e] = bb[e] - mu * sca;
  }
}

// ------------------------------------------------------------------
// tconv1x1: out_raw = U * hin * V^T per position, p-split halves.
// hin = affine(A) [+ affine(B)] [then PReLU(alpha)], applied on load.
// Grid: 512 = 256 pos-blocks x 2 halves (XCD-swizzled mates).
// ------------------------------------------------------------------
template<bool HASB, bool PRELU>
__global__ __launch_bounds__(256, 4)
void conv1x1_kernel(const float* __restrict__ rA, const float* __restrict__ scA,
                    const float* __restrict__ shA,
                    const float* __restrict__ rB, const float* __restrict__ scB,
                    const float* __restrict__ shB,
                    const float* __restrict__ alpha_ptr, int alpha_idx,
                    const float* __restrict__ U, const float* __restrict__ V,
                    float* __restrict__ out) {
  __shared__ float su[NP * 11], sv[121], sa[242], sb[242];
  int bid = blockIdx.x;
  int wg  = (bid & 7) * 64 + (bid >> 3);      // 512 % 8 == 0, bijective
  int ph = wg & 1, posblk = wg >> 1;
  int P0 = ph * 5;
  int t = threadIdx.x;
  if (t < 121) {
    sv[t] = V[t];
    sa[t] = scA[t]; sb[t] = shA[t];
    if (HASB) { sa[121 + t] = scB[t]; sb[121 + t] = shB[t]; }
  }
  if (t < NP * 11) {                           // su[pr*11+m] = U[(P0+pr)*11+m]
    su[t] = U[P0 * 11 + t];
  }
  __syncthreads();
  float alpha = 0.f;
  if (PRELU) alpha = alpha_ptr[alpha_idx];
  size_t pos = (size_t)posblk * 256 + t;

  float T[NP][11];
#pragma unroll
  for (int p = 0; p < NP; ++p)
#pragma unroll
    for (int n = 0; n < 11; ++n) T[p][n] = 0.f;

#pragma unroll
  for (int m = 0; m < 11; ++m) {
    float Xr[11];
#pragma unroll
    for (int n = 0; n < 11; ++n) {
      int e = m * 11 + n;
      float v = sa[e] * rA[(size_t)e * NPOS + pos] + sb[e];
      if (HASB) v += sa[121 + e] * rB[(size_t)e * NPOS + pos] + sb[121 + e];
      if (PRELU) v = v >= 0.f ? v : alpha * v;
      Xr[n] = v;
    }
#pragma unroll
    for (int p = 0; p < NP; ++p) {
      float u = su[p * 11 + m];
#pragma unroll
      for (int n = 0; n < 11; ++n) T[p][n] += u * Xr[n];
    }
  }
#pragma unroll
  for (int q = 0; q < 11; ++q) {
    float Yc[NP];
#pragma unroll
    for (int p = 0; p < NP; ++p) Yc[p] = 0.f;
#pragma unroll
    for (int n = 0; n < 11; ++n) {
      float v = sv[q * 11 + n];
#pragma unroll
      for (int p = 0; p < NP; ++p) Yc[p] += T[p][n] * v;
    }
#pragma unroll
    for (int p = 0; p < NP; ++p)
      out[(size_t)((P0 + p) * 11 + q) * NPOS + pos] = Yc[p];
  }
}

// ------------------------------------------------------------------
// tconv3x3, p-split halves. Grid: 512 = 256 pos-blocks x 2 halves.
// Per thread: Y[6][11]=66 + T[6][4]=24 regs.
// ------------------------------------------------------------------
template<int N0, int NW>
__device__ __forceinline__ void c3_chunk(const float* __restrict__ rA,
    const float* __restrict__ sa, const float* __restrict__ sh,
    const float* __restrict__ su, const float* __restrict__ sv,
    float alpha, int npos, float (&Y)[NP][11]) {
  float T[NP][NW];
#pragma unroll
  for (int p = 0; p < NP; ++p)
#pragma unroll
    for (int k = 0; k < NW; ++k) T[p][k] = 0.f;
#pragma unroll
  for (int m = 0; m < 11; ++m) {
    float Xr[NW];
#pragma unroll
    for (int k = 0; k < NW; ++k) {
      int e = m * 11 + N0 + k;
      float v = sa[e] * rA[(size_t)e * NPOS + npos] + sh[e];
      Xr[k] = v >= 0.f ? v : alpha * v;
    }
#pragma unroll
    for (int p = 0; p < NP; ++p) {
      float u = su[p * 11 + m];
#pragma unroll
      for (int k = 0; k < NW; ++k) T[p][k] += u * Xr[k];
    }
  }
#pragma unroll
  for (int k = 0; k < NW; ++k) {
#pragma unroll
    for (int q = 0; q < 11; ++q) {
      float v = sv[q * 11 + N0 + k];
#pragma unroll
      for (int p = 0; p < NP; ++p) Y[p][q] += T[p][k] * v;
    }
  }
}

__global__ __launch_bounds__(256, 4)
void conv3x3_kernel(const float* __restrict__ rA, const float* __restrict__ scA,
                    const float* __restrict__ shA,
                    const float* __restrict__ alpha_ptr, int alpha_idx,
                    const float* __restrict__ U, const float* __restrict__ V,
                    float* __restrict__ out) {
  __shared__ float su[9 * NP * 11], sv[1089], sa[121], sh[121];
  int bid = blockIdx.x;
  int wg  = (bid & 7) * 64 + (bid >> 3);
  int ph = wg & 1, posblk = wg >> 1;
  int P0 = ph * 5;
  int t = threadIdx.x;
  for (int idx = t; idx < 9 * NP * 11; idx += 256) {
    int ij = idx / (NP * 11), r = idx - ij * (NP * 11);   // r = pr*11+m
    su[idx] = U[ij * 121 + P0 * 11 + r];
  }
  for (int idx = t; idx < 1089; idx += 256) sv[idx] = V[idx];
  if (t < 121) { sa[t] = scA[t]; sh[t] = shA[t]; }
  __syncthreads();
  float alpha = alpha_ptr[alpha_idx];
  int pos = posblk * 256 + t;
  int b = pos >> 10, h = (pos >> 5) & 31, w = pos & 31;

  float Y[NP][11];
#pragma unroll
  for (int p = 0; p < NP; ++p)
#pragma unroll
    for (int q = 0; q < 11; ++q) Y[p][q] = 0.f;

  for (int ij = 0; ij < 9; ++ij) {
    int i = ij / 3, j = ij - 3 * (ij / 3);
    int hi = h + i - 1, wj = w + j - 1;
    if ((unsigned)hi >= 32u || (unsigned)wj >= 32u) continue;  // zero pad: tap = 0
    int npos = ((b << 5) + hi) * 32 + wj;
    const float* suij = &su[ij * NP * 11];
    const float* svij = &sv[ij * 121];
    c3_chunk<0, 4>(rA, sa, sh, suij, svij, alpha, npos, Y);
    c3_chunk<4, 4>(rA, sa, sh, suij, svij, alpha, npos, Y);
    c3_chunk<8, 3>(rA, sa, sh, suij, svij, alpha, npos, Y);
  }
#pragma unroll
  for (int p = 0; p < NP; ++p)
#pragma unroll
    for (int q = 0; q < 11; ++q)
      out[(size_t)((P0 + p) * 11 + q) * NPOS + pos] = Y[p][q];
}

// ------------------------------------------------------------------
// fcn head: out[b,o,h,w] = sum_e h[e]*W[o,e]; h = affine(A)+affine(B).
// Streams e with acc[21] (low registers). Grid 256.
// ------------------------------------------------------------------
__global__ __launch_bounds__(256, 4)
void head_kernel(const float* __restrict__ rA, const float* __restrict__ scA,
                 const float* __restrict__ shA,
                 const float* __restrict__ rB, const float* __restrict__ scB,
                 const float* __restrict__ shB,
                 const float* __restrict__ W, float* __restrict__ out) {
  __shared__ float sw[21 * 121], sa[242], sh[242];
  int t = threadIdx.x;
  for (int idx = t; idx < 2541; idx += 256) sw[idx] = W[idx];
  if (t < 121) {
    sa[t] = scA[t]; sh[t] = shA[t];
    sa[121 + t] = scB[t]; sh[121 + t] = shB[t];
  }
  __syncthreads();
  size_t pos = (size_t)blockIdx.x * 256 + t;
  int b = (int)(pos >> 10), hw = (int)(pos & 1023);
  float acc[21];
#pragma unroll
  for (int o = 0; o < 21; ++o) acc[o] = 0.f;
  for (int e = 0; e < 121; ++e) {
    float v = sa[e] * rA[(size_t)e * NPOS + pos] + sh[e] +
              sa[121 + e] * rB[(size_t)e * NPOS + pos] + sh[121 + e];
#pragma unroll
    for (int o = 0; o < 21; ++o) acc[o] += v * sw[o * 121 + e];
  }
#pragma unroll
  for (int o = 0; o < 21; ++o)
    out[(size_t)(b * 21 + o) * 1024 + hw] = acc[o];
}

// ------------------------------------------------------------------
extern "C" void kernel_launch(void* const* d_in, const int* in_sizes, int n_in,
                              void* d_out, int out_size, void* d_ws, size_t ws_size,
                              hipStream_t stream) {
  (void)in_sizes; (void)n_in; (void)out_size; (void)ws_size;
  const float* x     = (const float*)d_in[0];
  const float* f0_U  = (const float*)d_in[1];
  const float* f0_V  = (const float*)d_in[2];
  const float* f0_g  = (const float*)d_in[3];
  const float* f0_b  = (const float*)d_in[4];
  const float* f0_a  = (const float*)d_in[5];
  const float* s_U   = (const float*)d_in[6];
  const float* s_V   = (const float*)d_in[7];
  const float* s_g   = (const float*)d_in[8];
  const float* s_b   = (const float*)d_in[9];
  const float* bU1   = (const float*)d_in[10];
  const float* bV1   = (const float*)d_in[11];
  const float* bg1   = (const float*)d_in[12];
  const float* bb1   = (const float*)d_in[13];
  const float* ba1   = (const float*)d_in[14];
  const float* bU2   = (const float*)d_in[15];
  const float* bV2   = (const float*)d_in[16];
  const float* bg2   = (const float*)d_in[17];
  const float* bb2   = (const float*)d_in[18];
  const float* ba2   = (const float*)d_in[19];
  const float* bU3   = (const float*)d_in[20];
  const float* bV3   = (const float*)d_in[21];
  const float* bg3   = (const float*)d_in[22];
  const float* bb3   = (const float*)d_in[23];
  const float* headW = (const float*)d_in[24];

  float* ws = (float*)d_ws;
  const size_t BUF = (size_t)NE * NPOS;           // 7,929,856 floats per buffer
  float* B[4] = { ws, ws + BUF, ws + 2 * BUF, ws + 3 * BUF };
  float* st   = ws + 4 * BUF;                     // 17 ops * (scale121 + shift121)
  float* part = st + 17 * 242;                    // 968 floats of partial sums

  auto SCp = [&](int op) { return st + op * 242; };
  auto SHp = [&](int op) { return st + op * 242 + 121; };
  auto run_stats = [&](const float* raw, const float* g, const float* bb, int op) {
    stats_partial<<<484, 256, 0, stream>>>(raw, part);
    stats_final<<<1, 128, 0, stream>>>(part, g, bb, SCp(op), SHp(op));
  };

  // ---- f0 ----
  f0_kernel<<<4096, 256, 0, stream>>>(x, f0_U, f0_V, B[0]);
  run_stats(B[0], f0_g, f0_b, 0);

  // buffer rotation: for each block k -> {idn, z1, z2, z3} buffer index
  const int bufs[4][4] = { {1,2,3,0}, {2,3,0,1}, {3,0,1,2}, {0,1,2,3} };

  const float* hA   = B[0];  const float* hAsc = SCp(0); const float* hAsh = SHp(0);
  const float* hB   = nullptr; const float* hBsc = nullptr; const float* hBsh = nullptr;

  for (int k = 0; k < 4; ++k) {
    float* idn = B[bufs[k][0]];
    float* z1  = B[bufs[k][1]];
    float* z2  = B[bufs[k][2]];
    float* z3  = B[bufs[k][3]];
    int op_idn = 1 + k * 4, op_z1 = 2 + k * 4, op_z2 = 3 + k * 4, op_z3 = 4 + k * 4;

    if (k == 0) {  // h0 = prelu(tbn(y), f0_a): single source + prelu
      conv1x1_kernel<false, true><<<512, 256, 0, stream>>>(
          hA, hAsc, hAsh, nullptr, nullptr, nullptr, f0_a, 0,
          s_U + k * 121, s_V + k * 121, idn);
      conv1x1_kernel<false, true><<<512, 256, 0, stream>>>(
          hA, hAsc, hAsh, nullptr, nullptr, nullptr, f0_a, 0,
          bU1 + k * 121, bV1 + k * 121, z1);
    } else {       // h = tbn(z3_prev) + tbn(idn_prev): two sources, no prelu
      conv1x1_kernel<true, false><<<512, 256, 0, stream>>>(
          hA, hAsc, hAsh, hB, hBsc, hBsh, nullptr, 0,
          s_U + k * 121, s_V + k * 121, idn);
      conv1x1_kernel<true, false><<<512, 256, 0, stream>>>(
          hA, hAsc, hAsh, hB, hBsc, hBsh, nullptr, 0,
          bU1 + k * 121, bV1 + k * 121, z1);
    }
    run_stats(idn, s_g + k * 121, s_b + k * 121, op_idn);
    run_stats(z1,  bg1 + k * 121, bb1 + k * 121, op_z1);

    conv3x3_kernel<<<512, 256, 0, stream>>>(
        z1, SCp(op_z1), SHp(op_z1), ba1, k,
        bU2 + k * 1089, bV2 + k * 1089, z2);
    run_stats(z2, bg2 + k * 121, bb2 + k * 121, op_z2);

    conv1x1_kernel<false, true><<<512, 256, 0, stream>>>(
        z2, SCp(op_z2), SHp(op_z2), nullptr, nullptr, nullptr, ba2, k,
        bU3 + k * 121, bV3 + k * 121, z3);
    run_stats(z3, bg3 + k * 121, bb3 + k * 121, op_z3);

    hA = z3;  hAsc = SCp(op_z3);  hAsh = SHp(op_z3);
    hB = idn; hBsc = SCp(op_idn); hBsh = SHp(op_idn);
  }

  head_kernel<<<256, 256, 0, stream>>>(hA, hAsc, hAsh, hB, hBsc, hBsh,
                                       headW, (float*)d_out);
}

// Round 3
// 12032.100 us; speedup vs baseline: 1.3324x; 1.3324x over previous
//
#include <hip/hip_runtime.h>

#define NPOS 65536   // 64 batches * 32 * 32 positions
#define NE   121     // 11*11 tensor entries
#define NP   6       // p-rows per half for split kernels (P0 = ph*5; row 5 dup)

// ------------------------------------------------------------------
// f0: 8-channel 3x3 tensorized conv, 16x16 -> 11x11, writes raw y.
// Grid: 2048 blocks = (b,h), XCD-swizzled. Block: 256 thr = (c, w).
// Full Y[11][11] per thread; waves_per_eu(2,2) pins the allocator at a
// 256-VGPR budget (~185 live) so it does NOT spill to reach occupancy.
// ------------------------------------------------------------------
__global__ __attribute__((amdgpu_flat_work_group_size(256, 256)))
__attribute__((amdgpu_waves_per_eu(2, 2)))
void f0_kernel(const float* __restrict__ x, const float* __restrict__ U,
               const float* __restrict__ V, float* __restrict__ y) {
  __shared__ float smem[2816];                // U(1408) + V(1408); reused for reduce
  int bid = blockIdx.x;
  int wg  = (bid & 7) * 256 + (bid >> 3);     // bijective, 2048 % 8 == 0
  int b = wg >> 5, h = wg & 31;
  int t = threadIdx.x;
  int c = t >> 5, w = t & 31;

  float Y[11][11];
#pragma unroll
  for (int p = 0; p < 11; ++p)
#pragma unroll
    for (int q = 0; q < 11; ++q) Y[p][q] = 0.f;

  for (int ij = 0; ij < 9; ++ij) {
    __syncthreads();
    for (int idx = t; idx < 1408; idx += 256) {
      int cc = idx / 176, pm = idx % 176;     // U[c][ij][p][m] : (c*9+ij)*176 + p*16+m
      smem[idx]        = U[(cc * 9 + ij) * 176 + pm];
      smem[1408 + idx] = V[(cc * 9 + ij) * 176 + pm];
    }
    __syncthreads();
    int i = ij / 3, j = ij - 3 * (ij / 3);
    int hi = h + i - 1, wj = w + j - 1;
    if ((unsigned)hi < 32u && (unsigned)wj < 32u) {
      const float* xb = x + ((size_t)(b * 8 + c) << 18) + (hi << 5) + wj;
      const float* uB = &smem[c * 176];
      const float* vB = &smem[1408 + c * 176];
      for (int nc = 0; nc < 4; ++nc) {        // n in chunks of 4 (register economy)
        float A[11][4];
#pragma unroll
        for (int p = 0; p < 11; ++p)
#pragma unroll
          for (int k = 0; k < 4; ++k) A[p][k] = 0.f;
        for (int m = 0; m < 16; ++m) {
          float Xr[4];
#pragma unroll
          for (int k = 0; k < 4; ++k)
            Xr[k] = xb[(m * 16 + nc * 4 + k) << 10];
#pragma unroll
          for (int p = 0; p < 11; ++p) {
            float u = uB[p * 16 + m];
#pragma unroll
            for (int k = 0; k < 4; ++k) A[p][k] += u * Xr[k];
          }
        }
#pragma unroll
        for (int k = 0; k < 4; ++k) {
#pragma unroll
          for (int q = 0; q < 11; ++q) {
            float vv = vB[q * 16 + nc * 4 + k];
#pragma unroll
            for (int p = 0; p < 11; ++p) Y[p][q] += A[p][k] * vv;
          }
        }
      }
    }
  }

  // reduce over c (8 threads per (w,q)) through LDS, one p-row at a time
  int posb = ((b << 5) + h) << 5;
#pragma unroll
  for (int p = 0; p < 11; ++p) {
    __syncthreads();
#pragma unroll
    for (int q = 0; q < 11; ++q) smem[(c * 32 + w) * 11 + q] = Y[p][q];
    __syncthreads();
    for (int idx = t; idx < 352; idx += 256) {
      int qq = idx >> 5, w2 = idx & 31;
      float s = 0.f;
#pragma unroll
      for (int cc = 0; cc < 8; ++cc) s += smem[(cc * 32 + w2) * 11 + qq];
      y[(size_t)(p * 11 + qq) * NPOS + posb + w2] = s;
    }
  }
}

// ------------------------------------------------------------------
// TBN stats: partial sums (484 blocks), then finalize scale/shift.
// ------------------------------------------------------------------
__global__ __launch_bounds__(256)
void stats_partial(const float* __restrict__ raw, float* __restrict__ part) {
  int blk = blockIdx.x;
  int e = blk >> 2, qt = blk & 3;
  const float4* p = (const float4*)(raw + (size_t)e * NPOS) + qt * 4096;
  int t = threadIdx.x;
  float s = 0.f, s2 = 0.f;
  for (int i = t; i < 4096; i += 256) {
    float4 v = p[i];
    s  += v.x + v.y + v.z + v.w;
    s2 += v.x * v.x + v.y * v.y + v.z * v.z + v.w * v.w;
  }
#pragma unroll
  for (int o = 32; o > 0; o >>= 1) {
    s  += __shfl_down(s, o);
    s2 += __shfl_down(s2, o);
  }
  __shared__ float ls[8];
  int wid = t >> 6;
  if ((t & 63) == 0) { ls[wid] = s; ls[4 + wid] = s2; }
  __syncthreads();
  if (t == 0) {
    part[blk]       = ls[0] + ls[1] + ls[2] + ls[3];
    part[484 + blk] = ls[4] + ls[5] + ls[6] + ls[7];
  }
}

__global__ void stats_final(const float* __restrict__ part, const float* __restrict__ g,
                            const float* __restrict__ bb, float* __restrict__ sc,
                            float* __restrict__ sh) {
  int e = threadIdx.x;
  if (e < 121) {
    float s  = part[e * 4] + part[e * 4 + 1] + part[e * 4 + 2] + part[e * 4 + 3];
    float s2 = part[484 + e * 4] + part[484 + e * 4 + 1] +
               part[484 + e * 4 + 2] + part[484 + e * 4 + 3];
    float mu  = s  * (1.f / 65536.f);
    float var = s2 * (1.f / 65536.f) - mu * mu;
    float sca = g[e] * rsqrtf(var + 1e-5f);
    sc[e] = sca;
    sh[e] = bb[e] - mu * sca;
  }
}

// ------------------------------------------------------------------
// tconv1x1: out_raw = U * hin * V^T per position, p-split halves.
// hin = affine(A) [+ affine(B)] [then PReLU(alpha)], applied on load.
// Grid: 512 = 256 pos-blocks x 2 halves (XCD-swizzled mates).
// ~95 live regs; waves_per_eu(4,4) -> 128 budget, no spill.
// ------------------------------------------------------------------
template<bool HASB, bool PRELU>
__global__ __attribute__((amdgpu_flat_work_group_size(256, 256)))
__attribute__((amdgpu_waves_per_eu(4, 4)))
void conv1x1_kernel(const float* __restrict__ rA, const float* __restrict__ scA,
                    const float* __restrict__ shA,
                    const float* __restrict__ rB, const float* __restrict__ scB,
                    const float* __restrict__ shB,
                    const float* __restrict__ alpha_ptr, int alpha_idx,
                    const float* __restrict__ U, const float* __restrict__ V,
                    float* __restrict__ out) {
  __shared__ float su[NP * 11], sv[121], sa[242], sb[242];
  int bid = blockIdx.x;
  int wg  = (bid & 7) * 64 + (bid >> 3);      // 512 % 8 == 0, bijective
  int ph = wg & 1, posblk = wg >> 1;
  int P0 = ph * 5;
  int t = threadIdx.x;
  if (t < 121) {
    sv[t] = V[t];
    sa[t] = scA[t]; sb[t] = shA[t];
    if (HASB) { sa[121 + t] = scB[t]; sb[121 + t] = shB[t]; }
  }
  if (t < NP * 11) su[t] = U[P0 * 11 + t];    // su[pr*11+m] = U[(P0+pr)*11+m]
  __syncthreads();
  float alpha = 0.f;
  if (PRELU) alpha = alpha_ptr[alpha_idx];
  size_t pos = (size_t)posblk * 256 + t;

  float T[NP][11];
#pragma unroll
  for (int p = 0; p < NP; ++p)
#pragma unroll
    for (int n = 0; n < 11; ++n) T[p][n] = 0.f;

#pragma unroll
  for (int m = 0; m < 11; ++m) {
    float Xr[11];
#pragma unroll
    for (int n = 0; n < 11; ++n) {
      int e = m * 11 + n;
      float v = sa[e] * rA[(size_t)e * NPOS + pos] + sb[e];
      if (HASB) v += sa[121 + e] * rB[(size_t)e * NPOS + pos] + sb[121 + e];
      if (PRELU) v = v >= 0.f ? v : alpha * v;
      Xr[n] = v;
    }
#pragma unroll
    for (int p = 0; p < NP; ++p) {
      float u = su[p * 11 + m];
#pragma unroll
      for (int n = 0; n < 11; ++n) T[p][n] += u * Xr[n];
    }
  }
#pragma unroll
  for (int q = 0; q < 11; ++q) {
    float Yc[NP];
#pragma unroll
    for (int p = 0; p < NP; ++p) Yc[p] = 0.f;
#pragma unroll
    for (int n = 0; n < 11; ++n) {
      float v = sv[q * 11 + n];
#pragma unroll
      for (int p = 0; p < NP; ++p) Yc[p] += T[p][n] * v;
    }
#pragma unroll
    for (int p = 0; p < NP; ++p)
      out[(size_t)((P0 + p) * 11 + q) * NPOS + pos] = Yc[p];
  }
}

// ------------------------------------------------------------------
// tconv3x3, p-split halves. Grid: 512 = 256 pos-blocks x 2 halves.
// ~115 live regs; waves_per_eu(3,3) -> ~170 budget, no spill.
// ------------------------------------------------------------------
template<int N0, int NW>
__device__ __forceinline__ void c3_chunk(const float* __restrict__ rA,
    const float* __restrict__ sa, const float* __restrict__ sh,
    const float* __restrict__ su, const float* __restrict__ sv,
    float alpha, int npos, float (&Y)[NP][11]) {
  float T[NP][NW];
#pragma unroll
  for (int p = 0; p < NP; ++p)
#pragma unroll
    for (int k = 0; k < NW; ++k) T[p][k] = 0.f;
#pragma unroll
  for (int m = 0; m < 11; ++m) {
    float Xr[NW];
#pragma unroll
    for (int k = 0; k < NW; ++k) {
      int e = m * 11 + N0 + k;
      float v = sa[e] * rA[(size_t)e * NPOS + npos] + sh[e];
      Xr[k] = v >= 0.f ? v : alpha * v;
    }
#pragma unroll
    for (int p = 0; p < NP; ++p) {
      float u = su[p * 11 + m];
#pragma unroll
      for (int k = 0; k < NW; ++k) T[p][k] += u * Xr[k];
    }
  }
#pragma unroll
  for (int k = 0; k < NW; ++k) {
#pragma unroll
    for (int q = 0; q < 11; ++q) {
      float v = sv[q * 11 + N0 + k];
#pragma unroll
      for (int p = 0; p < NP; ++p) Y[p][q] += T[p][k] * v;
    }
  }
}

__global__ __attribute__((amdgpu_flat_work_group_size(256, 256)))
__attribute__((amdgpu_waves_per_eu(3, 3)))
void conv3x3_kernel(const float* __restrict__ rA, const float* __restrict__ scA,
                    const float* __restrict__ shA,
                    const float* __restrict__ alpha_ptr, int alpha_idx,
                    const float* __restrict__ U, const float* __restrict__ V,
                    float* __restrict__ out) {
  __shared__ float su[9 * NP * 11], sv[1089], sa[121], sh[121];
  int bid = blockIdx.x;
  int wg  = (bid & 7) * 64 + (bid >> 3);
  int ph = wg & 1, posblk = wg >> 1;
  int P0 = ph * 5;
  int t = threadIdx.x;
  for (int idx = t; idx < 9 * NP * 11; idx += 256) {
    int ij = idx / (NP * 11), r = idx - ij * (NP * 11);   // r = pr*11+m
    su[idx] = U[ij * 121 + P0 * 11 + r];
  }
  for (int idx = t; idx < 1089; idx += 256) sv[idx] = V[idx];
  if (t < 121) { sa[t] = scA[t]; sh[t] = shA[t]; }
  __syncthreads();
  float alpha = alpha_ptr[alpha_idx];
  int pos = posblk * 256 + t;
  int b = pos >> 10, h = (pos >> 5) & 31, w = pos & 31;

  float Y[NP][11];
#pragma unroll
  for (int p = 0; p < NP; ++p)
#pragma unroll
    for (int q = 0; q < 11; ++q) Y[p][q] = 0.f;

  for (int ij = 0; ij < 9; ++ij) {
    int i = ij / 3, j = ij - 3 * (ij / 3);
    int hi = h + i - 1, wj = w + j - 1;
    if ((unsigned)hi >= 32u || (unsigned)wj >= 32u) continue;  // zero pad: tap = 0
    int npos = ((b << 5) + hi) * 32 + wj;
    const float* suij = &su[ij * NP * 11];
    const float* svij = &sv[ij * 121];
    c3_chunk<0, 4>(rA, sa, sh, suij, svij, alpha, npos, Y);
    c3_chunk<4, 4>(rA, sa, sh, suij, svij, alpha, npos, Y);
    c3_chunk<8, 3>(rA, sa, sh, suij, svij, alpha, npos, Y);
  }
#pragma unroll
  for (int p = 0; p < NP; ++p)
#pragma unroll
    for (int q = 0; q < 11; ++q)
      out[(size_t)((P0 + p) * 11 + q) * NPOS + pos] = Y[p][q];
}

// ------------------------------------------------------------------
// fcn head: out[b,o,h,w] = sum_e h[e]*W[o,e]; h = affine(A)+affine(B).
// ------------------------------------------------------------------
__global__ __attribute__((amdgpu_flat_work_group_size(256, 256)))
__attribute__((amdgpu_waves_per_eu(4, 4)))
void head_kernel(const float* __restrict__ rA, const float* __restrict__ scA,
                 const float* __restrict__ shA,
                 const float* __restrict__ rB, const float* __restrict__ scB,
                 const float* __restrict__ shB,
                 const float* __restrict__ W, float* __restrict__ out) {
  __shared__ float sw[21 * 121], sa[242], sh[242];
  int t = threadIdx.x;
  for (int idx = t; idx < 2541; idx += 256) sw[idx] = W[idx];
  if (t < 121) {
    sa[t] = scA[t]; sh[t] = shA[t];
    sa[121 + t] = scB[t]; sh[121 + t] = shB[t];
  }
  __syncthreads();
  size_t pos = (size_t)blockIdx.x * 256 + t;
  int b = (int)(pos >> 10), hw = (int)(pos & 1023);
  float acc[21];
#pragma unroll
  for (int o = 0; o < 21; ++o) acc[o] = 0.f;
  for (int e = 0; e < 121; ++e) {
    float v = sa[e] * rA[(size_t)e * NPOS + pos] + sh[e] +
              sa[121 + e] * rB[(size_t)e * NPOS + pos] + sh[121 + e];
#pragma unroll
    for (int o = 0; o < 21; ++o) acc[o] += v * sw[o * 121 + e];
  }
#pragma unroll
  for (int o = 0; o < 21; ++o)
    out[(size_t)(b * 21 + o) * 1024 + hw] = acc[o];
}

// ------------------------------------------------------------------
extern "C" void kernel_launch(void* const* d_in, const int* in_sizes, int n_in,
                              void* d_out, int out_size, void* d_ws, size_t ws_size,
                              hipStream_t stream) {
  (void)in_sizes; (void)n_in; (void)out_size; (void)ws_size;
  const float* x     = (const float*)d_in[0];
  const float* f0_U  = (const float*)d_in[1];
  const float* f0_V  = (const float*)d_in[2];
  const float* f0_g  = (const float*)d_in[3];
  const float* f0_b  = (const float*)d_in[4];
  const float* f0_a  = (const float*)d_in[5];
  const float* s_U   = (const float*)d_in[6];
  const float* s_V   = (const float*)d_in[7];
  const float* s_g   = (const float*)d_in[8];
  const float* s_b   = (const float*)d_in[9];
  const float* bU1   = (const float*)d_in[10];
  const float* bV1   = (const float*)d_in[11];
  const float* bg1   = (const float*)d_in[12];
  const float* bb1   = (const float*)d_in[13];
  const float* ba1   = (const float*)d_in[14];
  const float* bU2   = (const float*)d_in[15];
  const float* bV2   = (const float*)d_in[16];
  const float* bg2   = (const float*)d_in[17];
  const float* bb2   = (const float*)d_in[18];
  const float* ba2   = (const float*)d_in[19];
  const float* bU3   = (const float*)d_in[20];
  const float* bV3   = (const float*)d_in[21];
  const float* bg3   = (const float*)d_in[22];
  const float* bb3   = (const float*)d_in[23];
  const float* headW = (const float*)d_in[24];

  float* ws = (float*)d_ws;
  const size_t BUF = (size_t)NE * NPOS;           // 7,929,856 floats per buffer
  float* B[4] = { ws, ws + BUF, ws + 2 * BUF, ws + 3 * BUF };
  float* st   = ws + 4 * BUF;                     // 17 ops * (scale121 + shift121)
  float* part = st + 17 * 242;                    // 968 floats of partial sums

  auto SCp = [&](int op) { return st + op * 242; };
  auto SHp = [&](int op) { return st + op * 242 + 121; };
  auto run_stats = [&](const float* raw, const float* g, const float* bb, int op) {
    stats_partial<<<484, 256, 0, stream>>>(raw, part);
    stats_final<<<1, 128, 0, stream>>>(part, g, bb, SCp(op), SHp(op));
  };

  // ---- f0 ----
  f0_kernel<<<2048, 256, 0, stream>>>(x, f0_U, f0_V, B[0]);
  run_stats(B[0], f0_g, f0_b, 0);

  // buffer rotation: for each block k -> {idn, z1, z2, z3} buffer index
  const int bufs[4][4] = { {1,2,3,0}, {2,3,0,1}, {3,0,1,2}, {0,1,2,3} };

  const float* hA   = B[0];  const float* hAsc = SCp(0); const float* hAsh = SHp(0);
  const float* hB   = nullptr; const float* hBsc = nullptr; const float* hBsh = nullptr;

  for (int k = 0; k < 4; ++k) {
    float* idn = B[bufs[k][0]];
    float* z1  = B[bufs[k][1]];
    float* z2  = B[bufs[k][2]];
    float* z3  = B[bufs[k][3]];
    int op_idn = 1 + k * 4, op_z1 = 2 + k * 4, op_z2 = 3 + k * 4, op_z3 = 4 + k * 4;

    if (k == 0) {  // h0 = prelu(tbn(y), f0_a): single source + prelu
      conv1x1_kernel<false, true><<<512, 256, 0, stream>>>(
          hA, hAsc, hAsh, nullptr, nullptr, nullptr, f0_a, 0,
          s_U + k * 121, s_V + k * 121, idn);
      conv1x1_kernel<false, true><<<512, 256, 0, stream>>>(
          hA, hAsc, hAsh, nullptr, nullptr, nullptr, f0_a, 0,
          bU1 + k * 121, bV1 + k * 121, z1);
    } else {       // h = tbn(z3_prev) + tbn(idn_prev): two sources, no prelu
      conv1x1_kernel<true, false><<<512, 256, 0, stream>>>(
          hA, hAsc, hAsh, hB, hBsc, hBsh, nullptr, 0,
          s_U + k * 121, s_V + k * 121, idn);
      conv1x1_kernel<true, false><<<512, 256, 0, stream>>>(
          hA, hAsc, hAsh, hB, hBsc, hBsh, nullptr, 0,
          bU1 + k * 121, bV1 + k * 121, z1);
    }
    run_stats(idn, s_g + k * 121, s_b + k * 121, op_idn);
    run_stats(z1,  bg1 + k * 121, bb1 + k * 121, op_z1);

    conv3x3_kernel<<<512, 256, 0, stream>>>(
        z1, SCp(op_z1), SHp(op_z1), ba1, k,
        bU2 + k * 1089, bV2 + k * 1089, z2);
    run_stats(z2, bg2 + k * 121, bb2 + k * 121, op_z2);

    conv1x1_kernel<false, true><<<512, 256, 0, stream>>>(
        z2, SCp(op_z2), SHp(op_z2), nullptr, nullptr, nullptr, ba2, k,
        bU3 + k * 121, bV3 + k * 121, z3);
    run_stats(z3, bg3 + k * 121, bb3 + k * 121, op_z3);

    hA = z3;  hAsc = SCp(op_z3);  hAsh = SHp(op_z3);
    hB = idn; hBsc = SCp(op_idn); hBsh = SHp(op_idn);
  }

  head_kernel<<<256, 256, 0, stream>>>(hA, hAsc, hAsh, hB, hBsc, hBsh,
                                       headW, (float*)d_out);
}

// Round 4
// 3769.355 us; speedup vs baseline: 4.2530x; 3.1921x over previous
//
#include <hip/hip_runtime.h>

#define NPOS 65536   // 64 batches * 32 * 32 positions
#define NE   121     // 11*11 tensor entries
#define NP   6       // p-rows per half for split kernels (P0 = ph*5; row 5 dup)

// ------------------------------------------------------------------
// f0: 8-channel 3x3 tensorized conv, 16x16 -> 11x11, writes raw y.
// Grid: 4096 = (b,h) x 2 p-halves; swizzle keeps a row's two halves and
// h-neighbors on one XCD. Block: 256 thr = (c, w).
// Register budget (hard lesson R1-R3: allocator ceiling is 128 VGPRs):
// Y[6][11]=66 + A[6][4]=24 + Xr4 + ~10 addr ≈ 105 live -> fits 128.
// #pragma unroll 2 on the m-loop caps in-flight loads.
// ------------------------------------------------------------------
__global__ __launch_bounds__(256, 2)
void f0_kernel(const float* __restrict__ x, const float* __restrict__ U,
               const float* __restrict__ V, float* __restrict__ y) {
  __shared__ float smem[2816];                // su(768)+sv(1408); reduce reuses 2816
  int bid = blockIdx.x;
  int wg  = (bid & 7) * 512 + (bid >> 3);     // bijective, 4096 % 8 == 0
  int ph  = wg & 1;                           // p-half; mate is 8 bids away (same XCD)
  int row = wg >> 1;                          // (b,h)
  int b = row >> 5, h = row & 31;
  int P0 = ph * 5;
  int t = threadIdx.x;
  int c = t >> 5, w = t & 31;

  float* su = smem;           // [c][pr][m] : c*96 + pr*16 + m   (768)
  float* sv = smem + 768;     // [c][q][n]  : c*176 + q*16 + n   (1408)

  float Y[NP][11];
#pragma unroll
  for (int p = 0; p < NP; ++p)
#pragma unroll
    for (int q = 0; q < 11; ++q) Y[p][q] = 0.f;

  for (int ij = 0; ij < 9; ++ij) {
    __syncthreads();
    for (int idx = t; idx < 768; idx += 256) {
      int cc = idx / 96, r = idx - cc * 96;
      int pr = r >> 4, m = r & 15;
      su[idx] = U[(cc * 9 + ij) * 176 + (P0 + pr) * 16 + m];
    }
    for (int idx = t; idx < 1408; idx += 256) {
      int cc = idx / 176, qn = idx - cc * 176;
      sv[idx] = V[(cc * 9 + ij) * 176 + qn];
    }
    __syncthreads();
    int i = ij / 3, j = ij - 3 * (ij / 3);
    int hi = h + i - 1, wj = w + j - 1;
    if ((unsigned)hi < 32u && (unsigned)wj < 32u) {
      const float* xb = x + ((size_t)(b * 8 + c) << 18) + (hi << 5) + wj;
      const float* uB = &su[c * 96];
      const float* vB = &sv[c * 176];
      for (int nc = 0; nc < 4; ++nc) {        // n in chunks of 4
        float A[NP][4];
#pragma unroll
        for (int p = 0; p < NP; ++p)
#pragma unroll
          for (int k = 0; k < 4; ++k) A[p][k] = 0.f;
#pragma unroll 2
        for (int m = 0; m < 16; ++m) {
          float Xr[4];
#pragma unroll
          for (int k = 0; k < 4; ++k)
            Xr[k] = xb[(m * 16 + nc * 4 + k) << 10];
#pragma unroll
          for (int p = 0; p < NP; ++p) {
            float u = uB[p * 16 + m];
#pragma unroll
            for (int k = 0; k < 4; ++k) A[p][k] += u * Xr[k];
          }
        }
#pragma unroll
        for (int k = 0; k < 4; ++k) {
#pragma unroll
          for (int q = 0; q < 11; ++q) {
            float vv = vB[q * 16 + nc * 4 + k];
#pragma unroll
            for (int p = 0; p < NP; ++p) Y[p][q] += A[p][k] * vv;
          }
        }
      }
    }
  }

  // reduce over c (8 threads per (w,q)) through LDS, one p-row at a time
  int posb = ((b << 5) + h) << 5;
#pragma unroll
  for (int p = 0; p < NP; ++p) {
    __syncthreads();
#pragma unroll
    for (int q = 0; q < 11; ++q) smem[(c * 32 + w) * 11 + q] = Y[p][q];
    __syncthreads();
    for (int idx = t; idx < 352; idx += 256) {
      int qq = idx >> 5, w2 = idx & 31;
      float s = 0.f;
#pragma unroll
      for (int cc = 0; cc < 8; ++cc) s += smem[(cc * 32 + w2) * 11 + qq];
      y[(size_t)((P0 + p) * 11 + qq) * NPOS + posb + w2] = s;
    }
  }
}

// ------------------------------------------------------------------
// TBN stats: partial sums (484 blocks), then finalize scale/shift.
// ------------------------------------------------------------------
__global__ __launch_bounds__(256)
void stats_partial(const float* __restrict__ raw, float* __restrict__ part) {
  int blk = blockIdx.x;
  int e = blk >> 2, qt = blk & 3;
  const float4* p = (const float4*)(raw + (size_t)e * NPOS) + qt * 4096;
  int t = threadIdx.x;
  float s = 0.f, s2 = 0.f;
  for (int i = t; i < 4096; i += 256) {
    float4 v = p[i];
    s  += v.x + v.y + v.z + v.w;
    s2 += v.x * v.x + v.y * v.y + v.z * v.z + v.w * v.w;
  }
#pragma unroll
  for (int o = 32; o > 0; o >>= 1) {
    s  += __shfl_down(s, o);
    s2 += __shfl_down(s2, o);
  }
  __shared__ float ls[8];
  int wid = t >> 6;
  if ((t & 63) == 0) { ls[wid] = s; ls[4 + wid] = s2; }
  __syncthreads();
  if (t == 0) {
    part[blk]       = ls[0] + ls[1] + ls[2] + ls[3];
    part[484 + blk] = ls[4] + ls[5] + ls[6] + ls[7];
  }
}

__global__ void stats_final(const float* __restrict__ part, const float* __restrict__ g,
                            const float* __restrict__ bb, float* __restrict__ sc,
                            float* __restrict__ sh) {
  int e = threadIdx.x;
  if (e < 121) {
    float s  = part[e * 4] + part[e * 4 + 1] + part[e * 4 + 2] + part[e * 4 + 3];
    float s2 = part[484 + e * 4] + part[484 + e * 4 + 1] +
               part[484 + e * 4 + 2] + part[484 + e * 4 + 3];
    float mu  = s  * (1.f / 65536.f);
    float var = s2 * (1.f / 65536.f) - mu * mu;
    float sca = g[e] * rsqrtf(var + 1e-5f);
    sc[e] = sca;
    sh[e] = bb[e] - mu * sca;
  }
}

// ------------------------------------------------------------------
// tconv1x1: out_raw = U * hin * V^T per position, p-split halves.
// hin = affine(A) [+ affine(B)] [then PReLU(alpha)], applied on load.
// Grid: 512 = 256 pos-blocks x 2 halves. ~90 live regs -> fits 128.
// ------------------------------------------------------------------
template<bool HASB, bool PRELU>
__global__ __launch_bounds__(256, 2)
void conv1x1_kernel(const float* __restrict__ rA, const float* __restrict__ scA,
                    const float* __restrict__ shA,
                    const float* __restrict__ rB, const float* __restrict__ scB,
                    const float* __restrict__ shB,
                    const float* __restrict__ alpha_ptr, int alpha_idx,
                    const float* __restrict__ U, const float* __restrict__ V,
                    float* __restrict__ out) {
  __shared__ float su[NP * 11], sv[121], sa[242], sb[242];
  int bid = blockIdx.x;
  int wg  = (bid & 7) * 64 + (bid >> 3);      // 512 % 8 == 0, bijective
  int ph = wg & 1, posblk = wg >> 1;
  int P0 = ph * 5;
  int t = threadIdx.x;
  if (t < 121) {
    sv[t] = V[t];
    sa[t] = scA[t]; sb[t] = shA[t];
    if (HASB) { sa[121 + t] = scB[t]; sb[121 + t] = shB[t]; }
  }
  if (t < NP * 11) su[t] = U[P0 * 11 + t];    // su[pr*11+m] = U[(P0+pr)*11+m]
  __syncthreads();
  float alpha = 0.f;
  if (PRELU) alpha = alpha_ptr[alpha_idx];
  size_t pos = (size_t)posblk * 256 + t;

  float T[NP][11];
#pragma unroll
  for (int p = 0; p < NP; ++p)
#pragma unroll
    for (int n = 0; n < 11; ++n) T[p][n] = 0.f;

#pragma unroll 2
  for (int m = 0; m < 11; ++m) {
    float Xr[11];
#pragma unroll
    for (int n = 0; n < 11; ++n) {
      int e = m * 11 + n;
      float v = sa[e] * rA[(size_t)e * NPOS + pos] + sb[e];
      if (HASB) v += sa[121 + e] * rB[(size_t)e * NPOS + pos] + sb[121 + e];
      if (PRELU) v = v >= 0.f ? v : alpha * v;
      Xr[n] = v;
    }
#pragma unroll
    for (int p = 0; p < NP; ++p) {
      float u = su[p * 11 + m];
#pragma unroll
      for (int n = 0; n < 11; ++n) T[p][n] += u * Xr[n];
    }
  }
#pragma unroll
  for (int q = 0; q < 11; ++q) {
    float Yc[NP];
#pragma unroll
    for (int p = 0; p < NP; ++p) Yc[p] = 0.f;
#pragma unroll
    for (int n = 0; n < 11; ++n) {
      float v = sv[q * 11 + n];
#pragma unroll
      for (int p = 0; p < NP; ++p) Yc[p] += T[p][n] * v;
    }
#pragma unroll
    for (int p = 0; p < NP; ++p)
      out[(size_t)((P0 + p) * 11 + q) * NPOS + pos] = Yc[p];
  }
}

// ------------------------------------------------------------------
// tconv3x3, p-split halves. Grid: 512 = 256 pos-blocks x 2 halves.
// Y[6][11]=66 + T[6][4]=24 + Xr4 ≈ 105 live -> fits 128.
// ------------------------------------------------------------------
template<int N0, int NW>
__device__ __forceinline__ void c3_chunk(const float* __restrict__ rA,
    const float* __restrict__ sa, const float* __restrict__ sh,
    const float* __restrict__ su, const float* __restrict__ sv,
    float alpha, int npos, float (&Y)[NP][11]) {
  float T[NP][NW];
#pragma unroll
  for (int p = 0; p < NP; ++p)
#pragma unroll
    for (int k = 0; k < NW; ++k) T[p][k] = 0.f;
#pragma unroll 2
  for (int m = 0; m < 11; ++m) {
    float Xr[NW];
#pragma unroll
    for (int k = 0; k < NW; ++k) {
      int e = m * 11 + N0 + k;
      float v = sa[e] * rA[(size_t)e * NPOS + npos] + sh[e];
      Xr[k] = v >= 0.f ? v : alpha * v;
    }
#pragma unroll
    for (int p = 0; p < NP; ++p) {
      float u = su[p * 11 + m];
#pragma unroll
      for (int k = 0; k < NW; ++k) T[p][k] += u * Xr[k];
    }
  }
#pragma unroll
  for (int k = 0; k < NW; ++k) {
#pragma unroll
    for (int q = 0; q < 11; ++q) {
      float v = sv[q * 11 + N0 + k];
#pragma unroll
      for (int p = 0; p < NP; ++p) Y[p][q] += T[p][k] * v;
    }
  }
}

__global__ __launch_bounds__(256, 2)
void conv3x3_kernel(const float* __restrict__ rA, const float* __restrict__ scA,
                    const float* __restrict__ shA,
                    const float* __restrict__ alpha_ptr, int alpha_idx,
                    const float* __restrict__ U, const float* __restrict__ V,
                    float* __restrict__ out) {
  __shared__ float su[9 * NP * 11], sv[1089], sa[121], sh[121];
  int bid = blockIdx.x;
  int wg  = (bid & 7) * 64 + (bid >> 3);
  int ph = wg & 1, posblk = wg >> 1;
  int P0 = ph * 5;
  int t = threadIdx.x;
  for (int idx = t; idx < 9 * NP * 11; idx += 256) {
    int ij = idx / (NP * 11), r = idx - ij * (NP * 11);   // r = pr*11+m
    su[idx] = U[ij * 121 + P0 * 11 + r];
  }
  for (int idx = t; idx < 1089; idx += 256) sv[idx] = V[idx];
  if (t < 121) { sa[t] = scA[t]; sh[t] = shA[t]; }
  __syncthreads();
  float alpha = alpha_ptr[alpha_idx];
  int pos = posblk * 256 + t;
  int b = pos >> 10, h = (pos >> 5) & 31, w = pos & 31;

  float Y[NP][11];
#pragma unroll
  for (int p = 0; p < NP; ++p)
#pragma unroll
    for (int q = 0; q < 11; ++q) Y[p][q] = 0.f;

  for (int ij = 0; ij < 9; ++ij) {
    int i = ij / 3, j = ij - 3 * (ij / 3);
    int hi = h + i - 1, wj = w + j - 1;
    if ((unsigned)hi >= 32u || (unsigned)wj >= 32u) continue;  // zero pad: tap = 0
    int npos = ((b << 5) + hi) * 32 + wj;
    const float* suij = &su[ij * NP * 11];
    const float* svij = &sv[ij * 121];
    c3_chunk<0, 4>(rA, sa, sh, suij, svij, alpha, npos, Y);
    c3_chunk<4, 4>(rA, sa, sh, suij, svij, alpha, npos, Y);
    c3_chunk<8, 3>(rA, sa, sh, suij, svij, alpha, npos, Y);
  }
#pragma unroll
  for (int p = 0; p < NP; ++p)
#pragma unroll
    for (int q = 0; q < 11; ++q)
      out[(size_t)((P0 + p) * 11 + q) * NPOS + pos] = Y[p][q];
}

// ------------------------------------------------------------------
// fcn head: out[b,o,h,w] = sum_e h[e]*W[o,e]; h = affine(A)+affine(B).
// acc[21] + few temps ≈ 35 live regs.
// ------------------------------------------------------------------
__global__ __launch_bounds__(256, 2)
void head_kernel(const float* __restrict__ rA, const float* __restrict__ scA,
                 const float* __restrict__ shA,
                 const float* __restrict__ rB, const float* __restrict__ scB,
                 const float* __restrict__ shB,
                 const float* __restrict__ W, float* __restrict__ out) {
  __shared__ float sw[21 * 121], sa[242], sh[242];
  int t = threadIdx.x;
  for (int idx = t; idx < 2541; idx += 256) sw[idx] = W[idx];
  if (t < 121) {
    sa[t] = scA[t]; sh[t] = shA[t];
    sa[121 + t] = scB[t]; sh[121 + t] = shB[t];
  }
  __syncthreads();
  size_t pos = (size_t)blockIdx.x * 256 + t;
  int b = (int)(pos >> 10), hw = (int)(pos & 1023);
  float acc[21];
#pragma unroll
  for (int o = 0; o < 21; ++o) acc[o] = 0.f;
  for (int e = 0; e < 121; ++e) {
    float v = sa[e] * rA[(size_t)e * NPOS + pos] + sh[e] +
              sa[121 + e] * rB[(size_t)e * NPOS + pos] + sh[121 + e];
#pragma unroll
    for (int o = 0; o < 21; ++o) acc[o] += v * sw[o * 121 + e];
  }
#pragma unroll
  for (int o = 0; o < 21; ++o)
    out[(size_t)(b * 21 + o) * 1024 + hw] = acc[o];
}

// ------------------------------------------------------------------
extern "C" void kernel_launch(void* const* d_in, const int* in_sizes, int n_in,
                              void* d_out, int out_size, void* d_ws, size_t ws_size,
                              hipStream_t stream) {
  (void)in_sizes; (void)n_in; (void)out_size; (void)ws_size;
  const float* x     = (const float*)d_in[0];
  const float* f0_U  = (const float*)d_in[1];
  const float* f0_V  = (const float*)d_in[2];
  const float* f0_g  = (const float*)d_in[3];
  const float* f0_b  = (const float*)d_in[4];
  const float* f0_a  = (const float*)d_in[5];
  const float* s_U   = (const float*)d_in[6];
  const float* s_V   = (const float*)d_in[7];
  const float* s_g   = (const float*)d_in[8];
  const float* s_b   = (const float*)d_in[9];
  const float* bU1   = (const float*)d_in[10];
  const float* bV1   = (const float*)d_in[11];
  const float* bg1   = (const float*)d_in[12];
  const float* bb1   = (const float*)d_in[13];
  const float* ba1   = (const float*)d_in[14];
  const float* bU2   = (const float*)d_in[15];
  const float* bV2   = (const float*)d_in[16];
  const float* bg2   = (const float*)d_in[17];
  const float* bb2   = (const float*)d_in[18];
  const float* ba2   = (const float*)d_in[19];
  const float* bU3   = (const float*)d_in[20];
  const float* bV3   = (const float*)d_in[21];
  const float* bg3   = (const float*)d_in[22];
  const float* bb3   = (const float*)d_in[23];
  const float* headW = (const float*)d_in[24];

  float* ws = (float*)d_ws;
  const size_t BUF = (size_t)NE * NPOS;           // 7,929,856 floats per buffer
  float* B[4] = { ws, ws + BUF, ws + 2 * BUF, ws + 3 * BUF };
  float* st   = ws + 4 * BUF;                     // 17 ops * (scale121 + shift121)
  float* part = st + 17 * 242;                    // 968 floats of partial sums

  auto SCp = [&](int op) { return st + op * 242; };
  auto SHp = [&](int op) { return st + op * 242 + 121; };
  auto run_stats = [&](const float* raw, const float* g, const float* bb, int op) {
    stats_partial<<<484, 256, 0, stream>>>(raw, part);
    stats_final<<<1, 128, 0, stream>>>(part, g, bb, SCp(op), SHp(op));
  };

  // ---- f0 ----
  f0_kernel<<<4096, 256, 0, stream>>>(x, f0_U, f0_V, B[0]);
  run_stats(B[0], f0_g, f0_b, 0);

  // buffer rotation: for each block k -> {idn, z1, z2, z3} buffer index
  const int bufs[4][4] = { {1,2,3,0}, {2,3,0,1}, {3,0,1,2}, {0,1,2,3} };

  const float* hA   = B[0];  const float* hAsc = SCp(0); const float* hAsh = SHp(0);
  const float* hB   = nullptr; const float* hBsc = nullptr; const float* hBsh = nullptr;

  for (int k = 0; k < 4; ++k) {
    float* idn = B[bufs[k][0]];
    float* z1  = B[bufs[k][1]];
    float* z2  = B[bufs[k][2]];
    float* z3  = B[bufs[k][3]];
    int op_idn = 1 + k * 4, op_z1 = 2 + k * 4, op_z2 = 3 + k * 4, op_z3 = 4 + k * 4;

    if (k == 0) {  // h0 = prelu(tbn(y), f0_a): single source + prelu
      conv1x1_kernel<false, true><<<512, 256, 0, stream>>>(
          hA, hAsc, hAsh, nullptr, nullptr, nullptr, f0_a, 0,
          s_U + k * 121, s_V + k * 121, idn);
      conv1x1_kernel<false, true><<<512, 256, 0, stream>>>(
          hA, hAsc, hAsh, nullptr, nullptr, nullptr, f0_a, 0,
          bU1 + k * 121, bV1 + k * 121, z1);
    } else {       // h = tbn(z3_prev) + tbn(idn_prev): two sources, no prelu
      conv1x1_kernel<true, false><<<512, 256, 0, stream>>>(
          hA, hAsc, hAsh, hB, hBsc, hBsh, nullptr, 0,
          s_U + k * 121, s_V + k * 121, idn);
      conv1x1_kernel<true, false><<<512, 256, 0, stream>>>(
          hA, hAsc, hAsh, hB, hBsc, hBsh, nullptr, 0,
          bU1 + k * 121, bV1 + k * 121, z1);
    }
    run_stats(idn, s_g + k * 121, s_b + k * 121, op_idn);
    run_stats(z1,  bg1 + k * 121, bb1 + k * 121, op_z1);

    conv3x3_kernel<<<512, 256, 0, stream>>>(
        z1, SCp(op_z1), SHp(op_z1), ba1, k,
        bU2 + k * 1089, bV2 + k * 1089, z2);
    run_stats(z2, bg2 + k * 121, bb2 + k * 121, op_z2);

    conv1x1_kernel<false, true><<<512, 256, 0, stream>>>(
        z2, SCp(op_z2), SHp(op_z2), nullptr, nullptr, nullptr, ba2, k,
        bU3 + k * 121, bV3 + k * 121, z3);
    run_stats(z3, bg3 + k * 121, bb3 + k * 121, op_z3);

    hA = z3;  hAsc = SCp(op_z3);  hAsh = SHp(op_z3);
    hB = idn; hBsc = SCp(op_idn); hBsh = SHp(op_idn);
  }

  head_kernel<<<256, 256, 0, stream>>>(hA, hAsc, hAsh, hB, hBsc, hBsh,
                                       headW, (float*)d_out);
}